// Round 5
// baseline (416.128 us; speedup 1.0000x reference)
//
#include <hip/hip_runtime.h>
#include <math.h>

// ---------------------------------------------------------------------------
// REFT_Psi: B=65536 rows, DIM=64. 5 kernels:
//  kA  : mem-attn -> o_vec -> per-gate GRU constants; G=pe@pe^T, v=pe@pi, pisq
//  kB1 : fused: ctx GEMM (MFMA, A-frags direct from global) -> logits+tpe GEMM
//        (split-fp16 theta in regs) -> a0 diag-MFMA -> per-thread softmax/
//        quadratic-form epilogue + emotion MLP. 31.5 KB LDS, 4 blocks/CU.
//  kS  : reduce 1024 stress partials (fp64)
//  kE  : out2 += 0.001*stress -> e_theta
//  kC  : bi-GRU via MFMA; ABuf wave-private -> zero barriers in the m-loop.
// Algebra: a1=P^T G P; ti.pi=P.v; a2=sum P_l tpe_l (tpe folded into logits
// GEMM); a3=a1-2 ti.pi+pisq; stress row = a0-2a2+a1.
// ---------------------------------------------------------------------------

#define BATCH 65536
#define CTXD  384
#define NP    5
#define EPSV  1e-8f

typedef _Float16 h8 __attribute__((ext_vector_type(8)));
typedef _Float16 h4 __attribute__((ext_vector_type(4)));
typedef float f32x4 __attribute__((ext_vector_type(4)));

// output offsets (floats)
#define O0 0
#define O1 4194304
#define O2 12582912
#define O3 16777216
#define O4 16842752
#define O5 16908288

// workspace offsets (floats)
#define WS_STRESS 0
#define WS_PART   256
#define NPART     1024
#define WS_GICF   1536
#define WS_GICR   1792
#define WS_G      2048
#define WS_V      2080
#define WS_PISQ   2088

__device__ __forceinline__ float wsum(float v) {
#pragma unroll
  for (int m = 1; m < 64; m <<= 1) v += __shfl_xor(v, m, 64);
  return v;
}

__device__ __forceinline__ float sigmoidf_(float x) {
  return 1.f / (1.f + __expf(-x));
}
__device__ __forceinline__ float tanhf_(float x) {
  float e2 = __expf(-2.f * x);
  return 2.f / (1.f + e2) - 1.f;
}

__device__ __forceinline__ h4 cvt4(float4 v) {
  h4 o = {(_Float16)v.x, (_Float16)v.y, (_Float16)v.z, (_Float16)v.w};
  return o;
}
__device__ __forceinline__ h8 mk8(float4 a, float4 b) {
  h8 o = {(_Float16)a.x, (_Float16)a.y, (_Float16)a.z, (_Float16)a.w,
          (_Float16)b.x, (_Float16)b.y, (_Float16)b.z, (_Float16)b.w};
  return o;
}

// ---------------------------------------------------------------- kernel A
__global__ __launch_bounds__(256) void kA(
    const float* __restrict__ memory, const float* __restrict__ tw,
    const float* __restrict__ ipw, const float* __restrict__ ipb,
    const float* __restrict__ outw, const float* __restrict__ outb,
    const float* __restrict__ wihf, const float* __restrict__ bihf,
    const float* __restrict__ wihr, const float* __restrict__ bihr,
    const float* __restrict__ pe, const float* __restrict__ pi,
    float* __restrict__ ws)
{
  __shared__ float attn[16], mth[64], vv[64], ov[64];
  int t = threadIdx.x;
  if (t == 0) {
    float m = tw[0];
#pragma unroll
    for (int i = 1; i < 10; i++) m = fmaxf(m, tw[i]);
    float e[10]; float s = 0.f;
#pragma unroll
    for (int i = 0; i < 10; i++) { e[i] = __expf(tw[i] - m); s += e[i]; }
#pragma unroll
    for (int i = 0; i < 10; i++) attn[i] = e[i] / s;
  }
  if (t < 25) {
    int l = t / 5, m = t - l * 5;
    float s = 0.f;
    for (int d = 0; d < 64; d++) s += pe[l * 64 + d] * pe[m * 64 + d];
    ws[WS_G + t] = s;
  } else if (t >= 32 && t < 37) {
    int l = t - 32;
    float s = 0.f;
    for (int d = 0; d < 64; d++) s += pe[l * 64 + d] * pi[d];
    ws[WS_V + l] = s;
  } else if (t == 40) {
    float s = 0.f;
    for (int d = 0; d < 64; d++) s += pi[d] * pi[d];
    ws[WS_PISQ] = s;
  }
  __syncthreads();
  if (t < 64) {
    float a = 0.f;
#pragma unroll
    for (int m = 0; m < 10; m++) a += attn[m] * memory[m * 64 + t];
    mth[t] = a;
  }
  __syncthreads();
  if (t < 64) {
    float a = ipb[128 + t];
    for (int k = 0; k < 64; k++) a += mth[k] * ipw[(128 + t) * 64 + k];
    vv[t] = a;
  }
  __syncthreads();
  if (t < 64) {
    float a = outb[t];
    for (int k = 0; k < 64; k++) a += vv[k] * outw[t * 64 + k];
    ov[t] = a;
  }
  __syncthreads();
  if (t < 192) {
    float af = bihf[t], ar = bihr[t];
    for (int k = 0; k < 64; k++) {
      af += ov[k] * wihf[t * 130 + k];
      ar += ov[k] * wihr[t * 130 + k];
    }
    ws[WS_GICF + t] = af;
    ws[WS_GICR + t] = ar;
  }
}

// ---------------------------------------------------------------- kernel B1
// grid 1024, block 256 (4 waves), 64 rows/block, 4 blocks/CU.
// A-fragments straight from global (context, theta); only cxout transpose and
// wave-local mid use LDS. LDS = 9216+17408+4352+256+256 = 31488 B.
__global__ __launch_bounds__(256, 4) void kB1(
    const float* __restrict__ theta, const float* __restrict__ context,
    const float* __restrict__ ctxw, const float* __restrict__ ctxb,
    const float* __restrict__ idealw, const float* __restrict__ idealb,
    const float* __restrict__ pe,
    const float* __restrict__ w1, const float* __restrict__ b1,
    const float* __restrict__ w2, const float* __restrict__ b2,
    const float* __restrict__ fw, const float* __restrict__ fb,
    float* __restrict__ dout, float* __restrict__ ws)
{
  __shared__ __align__(16) _Float16 cxout[64 * 72];
  __shared__ __align__(16) _Float16 mid[64 * 136];
  __shared__ float Lb[64 * 17];
  __shared__ float a0b[64];
  __shared__ float parts[64];

  int t = threadIdx.x, lane = t & 63, wv = t >> 6;
  int q = lane >> 4, c = lane & 15;
  int Rbase = blockIdx.x << 6;

  // ---- B-fragments for ctx GEMM (wave owns cols 16wv..16wv+16) ----
  h8 bf[12];
  {
    const float* wp = ctxw + (size_t)(wv * 16 + c) * CTXD + q * 8;
#pragma unroll
    for (int ks = 0; ks < 12; ks++)
      bf[ks] = mk8(*(const float4*)(wp + ks * 32), *(const float4*)(wp + ks * 32 + 4));
  }
  float cbv = ctxb[wv * 16 + c];

  // ---- ctx GEMM: A-frags direct from global, 4 M-tiles ----
#pragma unroll
  for (int mt = 0; mt < 4; mt++) {
    const float* ap = context + (size_t)(Rbase + mt * 16 + c) * CTXD + q * 8;
    f32x4 acc = (f32x4)(0.f);
#pragma unroll
    for (int ks = 0; ks < 12; ks++) {
      h8 av = mk8(*(const float4*)(ap + ks * 32), *(const float4*)(ap + ks * 32 + 4));
      acc = __builtin_amdgcn_mfma_f32_16x16x32_f16(av, bf[ks], acc, 0, 0, 0);
    }
#pragma unroll
    for (int reg = 0; reg < 4; reg++)
      cxout[(mt * 16 + q * 4 + reg) * 72 + wv * 16 + c] = (_Float16)(acc[reg] + cbv);
  }

  // ---- theta hi/lo fragments in regs (rows 16wv+c: this wave's P3 band) ----
  h8 ah0, ah1, al0, al1;
  {
    const float* tp = theta + (size_t)(Rbase + 16 * wv + c) * 64;
    float4 t0 = *(const float4*)(tp + q * 8);
    float4 t1 = *(const float4*)(tp + q * 8 + 4);
    float4 t2 = *(const float4*)(tp + 32 + q * 8);
    float4 t3 = *(const float4*)(tp + 32 + q * 8 + 4);
    ah0 = mk8(t0, t1);
    ah1 = mk8(t2, t3);
    float4 l0 = {t0.x - (float)ah0[0], t0.y - (float)ah0[1], t0.z - (float)ah0[2], t0.w - (float)ah0[3]};
    float4 l1 = {t1.x - (float)ah0[4], t1.y - (float)ah0[5], t1.z - (float)ah0[6], t1.w - (float)ah0[7]};
    float4 l2 = {t2.x - (float)ah1[0], t2.y - (float)ah1[1], t2.z - (float)ah1[2], t2.w - (float)ah1[3]};
    float4 l3 = {t3.x - (float)ah1[4], t3.y - (float)ah1[5], t3.z - (float)ah1[6], t3.w - (float)ah1[7]};
    al0 = mk8(l0, l1);
    al1 = mk8(l2, l3);
  }

  // ---- B-fragments for logits/tpe GEMM: rows 0-4 iw, 5-9 pe-hi, 10-14 pe-lo
  h8 bw[4];
#pragma unroll
  for (int ks = 0; ks < 4; ks++) {
#pragma unroll
    for (int j = 0; j < 8; j++) {
      int k = ks * 32 + q * 8 + j;
      float v = 0.f;
      if (c < 5) v = idealw[c * 128 + k];
      else if (c < 10) { if (k < 64) v = pe[(c - 5) * 64 + k]; }
      else if (c < 15) {
        if (k < 64) { float p = pe[(c - 10) * 64 + k]; v = p - (float)(_Float16)p; }
      }
      bw[ks][j] = (_Float16)v;
    }
  }
  __syncthreads();   // cxout complete (cross-wave transpose)

  // ---- P3: wave wv owns rows [16wv,16wv+16) ----
  const _Float16* acp = &cxout[(16 * wv + c) * 72 + q * 8];
  h8 ac0 = *(const h8*)(acp);
  h8 ac1 = *(const h8*)(acp + 32);

  // logits + tpe
  f32x4 Lacc = (f32x4)(0.f);
  Lacc = __builtin_amdgcn_mfma_f32_16x16x32_f16(ah0, bw[0], Lacc, 0, 0, 0);
  Lacc = __builtin_amdgcn_mfma_f32_16x16x32_f16(ah1, bw[1], Lacc, 0, 0, 0);
  Lacc = __builtin_amdgcn_mfma_f32_16x16x32_f16(ac0, bw[2], Lacc, 0, 0, 0);
  Lacc = __builtin_amdgcn_mfma_f32_16x16x32_f16(ac1, bw[3], Lacc, 0, 0, 0);
  Lacc = __builtin_amdgcn_mfma_f32_16x16x32_f16(al0, bw[0], Lacc, 0, 0, 0);
  Lacc = __builtin_amdgcn_mfma_f32_16x16x32_f16(al1, bw[1], Lacc, 0, 0, 0);
#pragma unroll
  for (int reg = 0; reg < 4; reg++)
    Lb[(16 * wv + q * 4 + reg) * 17 + c] = Lacc[reg];

  // a0 = ||theta||^2 via diag: hi.hi + 2 hi.lo
  {
    f32x4 hh = (f32x4)(0.f), hl = (f32x4)(0.f);
    hh = __builtin_amdgcn_mfma_f32_16x16x32_f16(ah0, ah0, hh, 0, 0, 0);
    hh = __builtin_amdgcn_mfma_f32_16x16x32_f16(ah1, ah1, hh, 0, 0, 0);
    hl = __builtin_amdgcn_mfma_f32_16x16x32_f16(ah0, al0, hl, 0, 0, 0);
    hl = __builtin_amdgcn_mfma_f32_16x16x32_f16(ah1, al1, hl, 0, 0, 0);
    if ((lane >> 4) == ((lane & 15) >> 2)) {
      int j = lane & 15;
      a0b[16 * wv + j] = hh[j & 3] + 2.f * hl[j & 3];
    }
  }

  // ---- emotion MLP layer 1 ----
#pragma unroll
  for (int tn = 0; tn < 8; tn++) {
    const float* wp = w1 + (tn * 16 + c) * 64 + q * 8;
    h8 b0 = mk8(*(const float4*)(wp),      *(const float4*)(wp + 4));
    h8 b1f = mk8(*(const float4*)(wp + 32), *(const float4*)(wp + 36));
    f32x4 acc = (f32x4)(0.f);
    acc = __builtin_amdgcn_mfma_f32_16x16x32_f16(ah0, b0, acc, 0, 0, 0);
    acc = __builtin_amdgcn_mfma_f32_16x16x32_f16(ah1, b1f, acc, 0, 0, 0);
    float bv = b1[tn * 16 + c];
#pragma unroll
    for (int reg = 0; reg < 4; reg++)
      mid[(16 * wv + q * 4 + reg) * 136 + tn * 16 + c] = (_Float16)tanhf_(acc[reg] + bv);
  }

  // ---- MLP layer 2 (wave-local mid, no barrier) ----
  {
    const _Float16* am = &mid[(16 * wv + c) * 136 + q * 8];
    h8 m0 = *(const h8*)(am);
    h8 m1 = *(const h8*)(am + 32);
    h8 m2 = *(const h8*)(am + 64);
    h8 m3 = *(const h8*)(am + 96);
#pragma unroll
    for (int tn = 0; tn < 4; tn++) {
      const float* wp = w2 + (tn * 16 + c) * 128 + q * 8;
      f32x4 acc = (f32x4)(0.f);
#pragma unroll
      for (int ks = 0; ks < 4; ks++) {
        h8 b = mk8(*(const float4*)(wp + ks * 32), *(const float4*)(wp + ks * 32 + 4));
        h8 a = (ks == 0) ? m0 : (ks == 1) ? m1 : (ks == 2) ? m2 : m3;
        acc = __builtin_amdgcn_mfma_f32_16x16x32_f16(a, b, acc, 0, 0, 0);
      }
      float bv = b2[tn * 16 + c];
#pragma unroll
      for (int reg = 0; reg < 4; reg++) {
        int row = Rbase + 16 * wv + q * 4 + reg;
        dout[O2 + (row << 6) + tn * 16 + c] = fmaxf(acc[reg] + bv, 0.f);
      }
    }
  }

  // ---- per-row epilogue (lanes 0-15 own rows 16wv+lane) ----
  if (lane < 16) {
    int r = 16 * wv + lane;
    int row = Rbase + r;
    float L[NP], tpe[NP];
#pragma unroll
    for (int l = 0; l < NP; l++) {
      L[l]   = Lb[r * 17 + l] + idealb[l];
      tpe[l] = Lb[r * 17 + 5 + l] + Lb[r * 17 + 10 + l];
    }
    float mx = L[0];
#pragma unroll
    for (int l = 1; l < NP; l++) mx = fmaxf(mx, L[l]);
    float P[NP], s = 0.f;
#pragma unroll
    for (int l = 0; l < NP; l++) { P[l] = __expf(L[l] - mx); s += P[l]; }
    float inv = 1.f / s;
#pragma unroll
    for (int l = 0; l < NP; l++) P[l] *= inv;
#pragma unroll
    for (int l = 0; l < NP; l++) dout[O5 + row * NP + l] = P[l];

    float a2 = 0.f, tipi = 0.f;
#pragma unroll
    for (int l = 0; l < NP; l++) {
      a2   += P[l] * tpe[l];
      tipi += P[l] * ws[WS_V + l];
    }
    float a1 = 0.f;
#pragma unroll
    for (int l = 0; l < NP; l++) {
      float pl = P[l];
#pragma unroll
      for (int m = 0; m < NP; m++) a1 += pl * P[m] * ws[WS_G + l * 5 + m];
    }
    float a0 = a0b[r];
    float a3 = fmaxf(a1 - 2.f * tipi + ws[WS_PISQ], 0.f);

    float na = sqrtf(a0), nb = sqrtf(a1);
    float qq = 1.f / ((na + EPSV) * (nb + EPSV));
    float num = a2 * qq;
    float den = fmaxf(na * nb * qq, EPSV);
    dout[O3 + row] = num / den;
    float fq = sqrtf(a3);
    float om = tanhf_(fq * fw[0] + fb[0]) * (1.f + 0.1f * __sinf(fq));
    dout[O4 + row] = om;

    parts[r] = a0 - 2.f * a2 + a1;
  }
  __syncthreads();
  if (t == 0) {
    float s = 0.f;
    for (int r = 0; r < 64; r++) s += parts[r];
    ws[WS_PART + blockIdx.x] = s;
  }
}

// ---------------------------------------------------------------- kernel S
__global__ __launch_bounds__(256) void kS(float* __restrict__ ws)
{
  __shared__ double sd[256];
  int t = threadIdx.x;
  double a = 0.0;
  for (int i = t; i < NPART; i += 256) a += (double)ws[WS_PART + i];
  sd[t] = a;
  __syncthreads();
  for (int off = 128; off > 0; off >>= 1) {
    if (t < off) sd[t] += sd[t + off];
    __syncthreads();
  }
  if (t == 0) ws[WS_STRESS] = (float)sd[0];
}

// ---------------------------------------------------------------- kernel E
__global__ __launch_bounds__(256) void kE(float* __restrict__ dout,
                                          const float* __restrict__ ws)
{
  float sc = 0.001f * ws[WS_STRESS];
  int i = blockIdx.x * 256 + threadIdx.x;
  float4* p = (float4*)(dout + O2);
  float4 v = p[i];
  v.x += sc; v.y += sc; v.z += sc; v.w += sc;
  p[i] = v;
}

// ---------------------------------------------------------------- kernel C
// MFMA bi-GRU. grid (256, 2). ABuf is wave-private (wave stages its own
// 16-row band) -> zero barriers inside the m-loop; waves fully async.
__global__ __launch_bounds__(256) void kC(
    const float* __restrict__ theta, const float* __restrict__ hprev,
    const float* __restrict__ wihf, const float* __restrict__ whhf,
    const float* __restrict__ bhhf,
    const float* __restrict__ wihr, const float* __restrict__ whhr,
    const float* __restrict__ bhhr,
    const float* __restrict__ ws, float* __restrict__ dout)
{
  __shared__ __align__(16) _Float16 WRZ[128 * 136];
  __shared__ __align__(16) _Float16 WN [64 * 72];
  __shared__ __align__(16) _Float16 WHN[64 * 72];
  __shared__ __align__(16) _Float16 ABuf[64 * 136];
  __shared__ float cg[192], wes[192], wre[192], wom[192], bhn[64];
  __shared__ float sLDS[64], rLDS[64], oLDS[64];

  int t = threadIdx.x, lane = t & 63, wv = t >> 6;
  int q = lane >> 4, col = lane & 15;
  int dir = blockIdx.y;
  const float* WIH = dir ? wihr : wihf;
  const float* WHH = dir ? whhr : whhf;
  const float* BHH = dir ? bhhr : bhhf;
  const float* GIC = ws + (dir ? WS_GICR : WS_GICF);

  for (int idx = t; idx < 128 * 128; idx += 256) {
    int n = idx >> 7, k = idx & 127;
    float v = (k < 64) ? WIH[n * 130 + 64 + k] : WHH[n * 64 + (k - 64)];
    WRZ[n * 136 + k] = (_Float16)v;
  }
  for (int idx = t; idx < 64 * 64; idx += 256) {
    int n = idx >> 6, k = idx & 63;
    WN [n * 72 + k] = (_Float16)WIH[(128 + n) * 130 + 64 + k];
    WHN[n * 72 + k] = (_Float16)WHH[(128 + n) * 64 + k];
  }
  if (t < 192) {
    float s = 0.f;
    for (int k = 0; k < 64; k++) s += WIH[t * 130 + 64 + k];
    wes[t] = s;
    wre[t] = WIH[t * 130 + 128];
    wom[t] = WIH[t * 130 + 129];
    cg[t]  = GIC[t] + (t < 128 ? BHH[t] : 0.f);
  }
  if (t < 64) bhn[t] = BHH[128 + t];
  __syncthreads();   // weights staged (only block-wide barrier)

  for (int m = 0; m < 4; m++) {
    int Mbase = (blockIdx.x << 8) + (m << 6);

    // ---- wave-private staging: wave wv stages rows [16wv,16wv+16) ----
    for (int i = 0; i < 16; i++) {
      int lr = 16 * wv + i;
      int row = Mbase + lr;
      float ev = dout[O2 + (row << 6) + lane];
      float hv = hprev[dir * (BATCH * 64) + (row << 6) + lane];
      float sr = wsum(ev) * 0.015625f;
      ABuf[lr * 136 + lane]      = (_Float16)(ev - sr);
      ABuf[lr * 136 + 64 + lane] = (_Float16)hv;
      if (lane == 0) sLDS[lr] = sr;
    }
    if (lane < 16) {
      rLDS[16 * wv + lane] = dout[O3 + Mbase + 16 * wv + lane];
      oLDS[16 * wv + lane] = dout[O4 + Mbase + 16 * wv + lane];
    }
    // no barrier: ABuf/sLDS/rLDS/oLDS bands are wave-local

    const _Float16* arow = &ABuf[(16 * wv + col) * 136 + q * 8];
    h8 a0 = *(const h8*)(arow);
    h8 a1 = *(const h8*)(arow + 32);
    h8 a2 = *(const h8*)(arow + 64);
    h8 a3 = *(const h8*)(arow + 96);

    f32x4 accR[4], accZ[4], accN[4], accH[4];
#pragma unroll
    for (int td = 0; td < 4; td++) {
      accR[td] = (f32x4)(0.f); accZ[td] = (f32x4)(0.f);
      accN[td] = (f32x4)(0.f); accH[td] = (f32x4)(0.f);
    }
#pragma unroll
    for (int td = 0; td < 4; td++) {
      const _Float16* br = &WRZ[(td * 16 + col) * 136 + q * 8];
      accR[td] = __builtin_amdgcn_mfma_f32_16x16x32_f16(a0, *(const h8*)(br),      accR[td], 0, 0, 0);
      accR[td] = __builtin_amdgcn_mfma_f32_16x16x32_f16(a1, *(const h8*)(br + 32), accR[td], 0, 0, 0);
      accR[td] = __builtin_amdgcn_mfma_f32_16x16x32_f16(a2, *(const h8*)(br + 64), accR[td], 0, 0, 0);
      accR[td] = __builtin_amdgcn_mfma_f32_16x16x32_f16(a3, *(const h8*)(br + 96), accR[td], 0, 0, 0);
      const _Float16* bz = &WRZ[(64 + td * 16 + col) * 136 + q * 8];
      accZ[td] = __builtin_amdgcn_mfma_f32_16x16x32_f16(a0, *(const h8*)(bz),      accZ[td], 0, 0, 0);
      accZ[td] = __builtin_amdgcn_mfma_f32_16x16x32_f16(a1, *(const h8*)(bz + 32), accZ[td], 0, 0, 0);
      accZ[td] = __builtin_amdgcn_mfma_f32_16x16x32_f16(a2, *(const h8*)(bz + 64), accZ[td], 0, 0, 0);
      accZ[td] = __builtin_amdgcn_mfma_f32_16x16x32_f16(a3, *(const h8*)(bz + 96), accZ[td], 0, 0, 0);
      const _Float16* bn = &WN[(td * 16 + col) * 72 + q * 8];
      accN[td] = __builtin_amdgcn_mfma_f32_16x16x32_f16(a0, *(const h8*)(bn),      accN[td], 0, 0, 0);
      accN[td] = __builtin_amdgcn_mfma_f32_16x16x32_f16(a1, *(const h8*)(bn + 32), accN[td], 0, 0, 0);
      const _Float16* bh = &WHN[(td * 16 + col) * 72 + q * 8];
      accH[td] = __builtin_amdgcn_mfma_f32_16x16x32_f16(a2, *(const h8*)(bh),      accH[td], 0, 0, 0);
      accH[td] = __builtin_amdgcn_mfma_f32_16x16x32_f16(a3, *(const h8*)(bh + 32), accH[td], 0, 0, 0);
    }

#pragma unroll
    for (int reg = 0; reg < 4; reg++) {
      int lr  = 16 * wv + q * 4 + reg;
      int row = Mbase + lr;
      float sr = sLDS[lr], rv = rLDS[lr], ov = oLDS[lr];
#pragma unroll
      for (int td = 0; td < 4; td++) {
        int d = td * 16 + col;
        float hv = (float)ABuf[lr * 136 + 64 + d];
        float A0 = accR[td][reg] + cg[d]       + sr * wes[d]       + rv * wre[d]       + ov * wom[d];
        float A1 = accZ[td][reg] + cg[64 + d]  + sr * wes[64 + d]  + rv * wre[64 + d]  + ov * wom[64 + d];
        float AN = accN[td][reg] + cg[128 + d] + sr * wes[128 + d] + rv * wre[128 + d] + ov * wom[128 + d];
        float AH = accH[td][reg] + bhn[d];
        float r  = sigmoidf_(A0);
        float z  = sigmoidf_(A1);
        float nn = tanhf_(AN + r * AH);
        float hf = (1.f - z) * nn + z * hv;
        dout[O1 + dir * (BATCH * 64) + (row << 6) + d] = hf;
        if (dir == 0) {
          dout[(row << 6) + d] = 0.3f * theta[(row << 6) + d] + 0.7f * hf;
        }
      }
    }
    // no trailing barrier: next m's ABuf writes are same-wave ordered
  }
}

// ---------------------------------------------------------------- launch
extern "C" void kernel_launch(void* const* d_in, const int* in_sizes, int n_in,
                              void* d_out, int out_size, void* d_ws, size_t ws_size,
                              hipStream_t stream)
{
  const float* theta   = (const float*)d_in[0];
  const float* context = (const float*)d_in[1];
  const float* h_prev  = (const float*)d_in[2];
  const float* memory  = (const float*)d_in[3];
  const float* tw      = (const float*)d_in[4];
  const float* ipw     = (const float*)d_in[5];
  const float* ipb     = (const float*)d_in[6];
  const float* outw    = (const float*)d_in[7];
  const float* outb    = (const float*)d_in[8];
  const float* ew1     = (const float*)d_in[9];
  const float* eb1     = (const float*)d_in[10];
  const float* ew2     = (const float*)d_in[11];
  const float* eb2     = (const float*)d_in[12];
  const float* pe      = (const float*)d_in[13];
  const float* cw      = (const float*)d_in[14];
  const float* cb      = (const float*)d_in[15];
  const float* iw      = (const float*)d_in[16];
  const float* ib      = (const float*)d_in[17];
  const float* wihf    = (const float*)d_in[18];
  const float* whhf    = (const float*)d_in[19];
  const float* bihf    = (const float*)d_in[20];
  const float* bhhf    = (const float*)d_in[21];
  const float* wihr    = (const float*)d_in[22];
  const float* whhr    = (const float*)d_in[23];
  const float* bihr    = (const float*)d_in[24];
  const float* bhhr    = (const float*)d_in[25];
  const float* fw      = (const float*)d_in[26];
  const float* fb      = (const float*)d_in[27];
  const float* pi      = (const float*)d_in[28];
  float* dout = (float*)d_out;
  float* ws   = (float*)d_ws;

  kA<<<1, 256, 0, stream>>>(memory, tw, ipw, ipb, outw, outb, wihf, bihf,
                            wihr, bihr, pe, pi, ws);
  kB1<<<1024, 256, 0, stream>>>(theta, context, cw, cb, iw, ib, pe,
                                ew1, eb1, ew2, eb2, fw, fb, dout, ws);
  kS<<<1, 256, 0, stream>>>(ws);
  kE<<<4096, 256, 0, stream>>>(dout, ws);
  kC<<<dim3(256, 2, 1), 256, 0, stream>>>(theta, h_prev, wihf, whhf, bhhf,
                                          wihr, whhr, bhhr, ws, dout);
}